// Round 1
// baseline (2576.572 us; speedup 1.0000x reference)
//
#include <hip/hip_runtime.h>
#include <cstdint>
#include <cstddef>

#define DIMC     512
#define D_INNER  1024
#define HEADDIM  128
#define NHEADS   8
#define D_STATE  128
#define CONV_DIM 1280
#define D_IN_PROJ 2312
#define BSZ      4
#define LSEQ     4096
#define BLTOT    (BSZ*LSEQ)   // 16384

// ---------------- K1: in_proj GEMM ----------------
// zxbcdt[m, e] = sum_d x[b, d, l] * W[e, d]   (m = b*4096 + l)
// split-written into zbuf (e<1024), xbc (1024<=e<2304), dtb (2304<=e<2312)
__global__ __launch_bounds__(256) void k1_inproj(
    const float* __restrict__ x, const float* __restrict__ W,
    float* __restrict__ zbuf, float* __restrict__ xbc, float* __restrict__ dtb)
{
    __shared__ float As[32][68];
    __shared__ float Bs[32][68];
    const int tx = threadIdx.x, ty = threadIdx.y;
    const int tid = ty * 16 + tx;
    const int n0 = blockIdx.x * 64;
    const int m0 = blockIdx.y * 64;
    const int b  = m0 >> 12;
    const int l0 = m0 & 4095;

    float c[4][4] = {};
    const int am = tid & 63, ak = tid >> 6;   // A loader: m, k-row
    const int bk = tid & 31, bn = tid >> 5;   // B loader: k, n-row(0..7)

    for (int kb = 0; kb < DIMC; kb += 32) {
        #pragma unroll
        for (int kk = 0; kk < 32; kk += 4) {
            As[ak + kk][am] = x[((size_t)(b * DIMC + kb + ak + kk) << 12) + l0 + am];
        }
        #pragma unroll
        for (int nn = 0; nn < 8; ++nn) {
            int n = bn * 8 + nn;
            int e = n0 + n;
            Bs[bk][n] = (e < D_IN_PROJ) ? W[(size_t)e * DIMC + kb + bk] : 0.f;
        }
        __syncthreads();
        #pragma unroll
        for (int kk = 0; kk < 32; ++kk) {
            float4 a4 = *(const float4*)&As[kk][ty * 4];
            float4 b4 = *(const float4*)&Bs[kk][tx * 4];
            float av_[4] = {a4.x, a4.y, a4.z, a4.w};
            float bv_[4] = {b4.x, b4.y, b4.z, b4.w};
            #pragma unroll
            for (int i = 0; i < 4; ++i)
                #pragma unroll
                for (int j = 0; j < 4; ++j)
                    c[i][j] = fmaf(av_[i], bv_[j], c[i][j]);
        }
        __syncthreads();
    }
    #pragma unroll
    for (int i = 0; i < 4; ++i) {
        int m = m0 + ty * 4 + i;
        #pragma unroll
        for (int j = 0; j < 4; ++j) {
            int e = n0 + tx * 4 + j;
            float v = c[i][j];
            if (e < D_INNER)                  zbuf[(size_t)m * D_INNER + e] = v;
            else if (e < D_INNER + CONV_DIM)  xbc[(size_t)m * CONV_DIM + (e - D_INNER)] = v;
            else if (e < D_IN_PROJ)           dtb[(size_t)m * NHEADS + (e - (D_INNER + CONV_DIM))] = v;
        }
    }
}

// ---------------- K2: softplus(dt + bias), dA = exp(dtp * -exp(A_log)) ----------------
__global__ __launch_bounds__(256) void k2_dt(
    const float* __restrict__ dtb, const float* __restrict__ dt_bias,
    const float* __restrict__ A_log, float* __restrict__ dtp, float* __restrict__ dAb)
{
    int idx = blockIdx.x * 256 + threadIdx.x;
    if (idx >= BLTOT * NHEADS) return;
    int h = idx & 7;
    float v = dtb[idx] + dt_bias[h];
    float sp = (v > 20.f) ? v : log1pf(expf(v));
    dtp[idx] = sp;
    dAb[idx] = expf(sp * (-expf(A_log[h])));
}

// ---------------- K3: causal depthwise conv(4) + SiLU ----------------
__global__ __launch_bounds__(256) void k3_conv(
    const float* __restrict__ xbc, const float* __restrict__ cw,
    const float* __restrict__ cb, float* __restrict__ xbcc)
{
    int idx = blockIdx.x * 256 + threadIdx.x;   // BLTOT*CONV_DIM exact
    int c = idx % CONV_DIM;
    int m = idx / CONV_DIM;
    int l = m & 4095;
    float acc = cb[c];
    #pragma unroll
    for (int j = 0; j < 4; ++j) {
        if (l - j >= 0)
            acc = fmaf(xbc[(size_t)(m - j) * CONV_DIM + c], cw[c * 4 + (3 - j)], acc);
    }
    xbcc[idx] = acc / (1.f + expf(-acc));
}

// ---------------- K4: sequential SSM scan ----------------
// wave = (b, h, p-quad). lane: p = pq*4 + (lane&3), n in [(lane>>2)*8, +8)
__global__ __launch_bounds__(256) void k4_scan(
    const float* __restrict__ xbcc, const float* __restrict__ dtp,
    const float* __restrict__ dAb, const float* __restrict__ Dp,
    float* __restrict__ ybuf)
{
    const int lane = threadIdx.x & 63;
    const int w  = blockIdx.x * 4 + (threadIdx.x >> 6);  // 0..1023
    const int pq = w & 31;
    const int h  = (w >> 5) & 7;
    const int b  = w >> 8;
    const int p  = pq * 4 + (lane & 3);
    const int nb = (lane >> 2) * 8;
    const float Dh = Dp[h];
    const size_t mbase = (size_t)b * LSEQ;

    constexpr int PF = 4;
    float4 B0[PF], B1[PF], C0[PF], C1[PF];
    float xv[PF], av[PF], dv[PF];

    auto issue = [&](int t, int slot) {
        const float* row = xbcc + (mbase + t) * CONV_DIM;
        B0[slot] = *(const float4*)(row + D_INNER + nb);
        B1[slot] = *(const float4*)(row + D_INNER + nb + 4);
        C0[slot] = *(const float4*)(row + D_INNER + D_STATE + nb);
        C1[slot] = *(const float4*)(row + D_INNER + D_STATE + nb + 4);
        xv[slot] = row[h * HEADDIM + p];
        av[slot] = dAb[(mbase + t) * NHEADS + h];
        dv[slot] = dtp[(mbase + t) * NHEADS + h];
    };
    #pragma unroll
    for (int t = 0; t < PF; ++t) issue(t, t);

    float s0=0.f,s1=0.f,s2=0.f,s3=0.f,s4=0.f,s5=0.f,s6=0.f,s7=0.f;

    #pragma unroll 4
    for (int t = 0; t < LSEQ; ++t) {
        const int slot = t & (PF - 1);
        const float4 b0 = B0[slot], b1 = B1[slot];
        const float4 c0 = C0[slot], c1 = C1[slot];
        const float xt = xv[slot], dAt = av[slot], dtt = dv[slot];
        if (t + PF < LSEQ) issue(t + PF, slot);

        const float dtx = dtt * xt;
        float y0, y1;
        s0 = fmaf(s0, dAt, dtx * b0.x); y0 = s0 * c0.x;
        s1 = fmaf(s1, dAt, dtx * b0.y); y1 = s1 * c0.y;
        s2 = fmaf(s2, dAt, dtx * b0.z); y0 = fmaf(s2, c0.z, y0);
        s3 = fmaf(s3, dAt, dtx * b0.w); y1 = fmaf(s3, c0.w, y1);
        s4 = fmaf(s4, dAt, dtx * b1.x); y0 = fmaf(s4, c1.x, y0);
        s5 = fmaf(s5, dAt, dtx * b1.y); y1 = fmaf(s5, c1.y, y1);
        s6 = fmaf(s6, dAt, dtx * b1.z); y0 = fmaf(s6, c1.z, y0);
        s7 = fmaf(s7, dAt, dtx * b1.w); y1 = fmaf(s7, c1.w, y1);
        float y = y0 + y1;
        y += __shfl_xor(y, 4);
        y += __shfl_xor(y, 8);
        y += __shfl_xor(y, 16);
        y += __shfl_xor(y, 32);
        if ((lane >> 2) == 0) {
            y = fmaf(Dh, xt, y);
            ybuf[(mbase + t) * D_INNER + h * HEADDIM + p] = y;
        }
    }
}

// ---------------- K5: y *= silu(z); RMSNorm * norm_w (in place) ----------------
__global__ __launch_bounds__(256) void k5_norm(
    float* __restrict__ ybuf, const float* __restrict__ zbuf, const float* __restrict__ nw)
{
    const int m = blockIdx.x;
    const int tid = threadIdx.x;
    const size_t off = (size_t)m * D_INNER + tid * 4;
    float4 yv = *(const float4*)(ybuf + off);
    float4 zv = *(const float4*)(zbuf + off);
    float4 g;
    g.x = yv.x * (zv.x / (1.f + expf(-zv.x)));
    g.y = yv.y * (zv.y / (1.f + expf(-zv.y)));
    g.z = yv.z * (zv.z / (1.f + expf(-zv.z)));
    g.w = yv.w * (zv.w / (1.f + expf(-zv.w)));
    float ss = g.x*g.x + g.y*g.y + g.z*g.z + g.w*g.w;
    #pragma unroll
    for (int mask = 1; mask <= 32; mask <<= 1) ss += __shfl_xor(ss, mask);
    __shared__ float red[4];
    if ((tid & 63) == 0) red[tid >> 6] = ss;
    __syncthreads();
    float tot = red[0] + red[1] + red[2] + red[3];
    float scale = rsqrtf(tot * (1.f / 1024.f) + 1e-5f);
    float4 w4 = *(const float4*)(nw + tid * 4);
    g.x *= scale * w4.x;
    g.y *= scale * w4.y;
    g.z *= scale * w4.z;
    g.w *= scale * w4.w;
    *(float4*)(ybuf + off) = g;
}

// ---------------- K6: out_proj GEMM + residual (transposed store) ----------------
// out[b, d, l] = x[b, d, l] + sum_e ynorm[m, e] * W[d, e]
__global__ __launch_bounds__(256) void k6_outproj(
    const float* __restrict__ y, const float* __restrict__ W,
    const float* __restrict__ x, float* __restrict__ out)
{
    __shared__ float As[32][68];  // [k][l-sub]
    __shared__ float Bs[32][68];  // [k][d-sub]
    const int tx = threadIdx.x, ty = threadIdx.y;
    const int tid = ty * 16 + tx;
    const int n0 = blockIdx.x * 64;   // d
    const int m0 = blockIdx.y * 64;   // m = b*4096 + l
    const int b  = m0 >> 12;
    const int l0 = m0 & 4095;

    float c[4][4] = {};
    const int lk = tid & 31, lr = tid >> 5;

    for (int kb = 0; kb < D_INNER; kb += 32) {
        #pragma unroll
        for (int mm = 0; mm < 8; ++mm) {
            int m = lr * 8 + mm;
            As[lk][m] = y[(size_t)(m0 + m) * D_INNER + kb + lk];
        }
        #pragma unroll
        for (int nn = 0; nn < 8; ++nn) {
            int n = lr * 8 + nn;
            Bs[lk][n] = W[(size_t)(n0 + n) * D_INNER + kb + lk];
        }
        __syncthreads();
        #pragma unroll
        for (int kk = 0; kk < 32; ++kk) {
            float4 a4 = *(const float4*)&As[kk][tx * 4];   // l-dim
            float4 b4 = *(const float4*)&Bs[kk][ty * 4];   // d-dim
            float av_[4] = {a4.x, a4.y, a4.z, a4.w};
            float bv_[4] = {b4.x, b4.y, b4.z, b4.w};
            #pragma unroll
            for (int i = 0; i < 4; ++i)
                #pragma unroll
                for (int j = 0; j < 4; ++j)
                    c[i][j] = fmaf(bv_[i], av_[j], c[i][j]);
        }
        __syncthreads();
    }
    #pragma unroll
    for (int i = 0; i < 4; ++i) {
        int d = n0 + ty * 4 + i;
        size_t o = ((size_t)(b * DIMC + d) << 12) + l0 + tx * 4;
        float4 xr = *(const float4*)(x + o);
        float4 r;
        r.x = c[i][0] + xr.x;
        r.y = c[i][1] + xr.y;
        r.z = c[i][2] + xr.z;
        r.w = c[i][3] + xr.w;
        *(float4*)(out + o) = r;
    }
}

extern "C" void kernel_launch(void* const* d_in, const int* in_sizes, int n_in,
                              void* d_out, int out_size, void* d_ws, size_t ws_size,
                              hipStream_t stream) {
    const float* x          = (const float*)d_in[0];
    const float* in_proj_w  = (const float*)d_in[1];
    const float* conv_w     = (const float*)d_in[2];
    const float* conv_b     = (const float*)d_in[3];
    const float* dt_bias    = (const float*)d_in[4];
    const float* A_log      = (const float*)d_in[5];
    const float* D_param    = (const float*)d_in[6];
    const float* norm_w     = (const float*)d_in[7];
    const float* out_proj_w = (const float*)d_in[8];
    float* out = (float*)d_out;

    float* ws   = (float*)d_ws;
    float* zbuf = ws;                                   // BLTOT*1024
    float* xbc  = zbuf + (size_t)BLTOT * D_INNER;       // BLTOT*1280 (pre-conv)
    float* xbcc = xbc  + (size_t)BLTOT * CONV_DIM;      // BLTOT*1280 (post conv+silu)
    float* dtb  = xbcc + (size_t)BLTOT * CONV_DIM;      // BLTOT*8
    float* dtp  = dtb  + (size_t)BLTOT * NHEADS;        // BLTOT*8
    float* dAb  = dtp  + (size_t)BLTOT * NHEADS;        // BLTOT*8
    float* ybuf = xbc;  // pre-conv xbc is dead after K3 -> reuse as scan output

    k1_inproj<<<dim3(37, 256), dim3(16, 16), 0, stream>>>(x, in_proj_w, zbuf, xbc, dtb);
    k2_dt<<<dim3(512), dim3(256), 0, stream>>>(dtb, dt_bias, A_log, dtp, dAb);
    k3_conv<<<dim3(81920), dim3(256), 0, stream>>>(xbc, conv_w, conv_b, xbcc);
    k4_scan<<<dim3(256), dim3(256), 0, stream>>>(xbcc, dtp, dAb, D_param, ybuf);
    k5_norm<<<dim3(BLTOT), dim3(256), 0, stream>>>(ybuf, zbuf, norm_w);
    k6_outproj<<<dim3(8, 256), dim3(16, 16), 0, stream>>>(ybuf, out_proj_w, x, out);
}